// Round 14
// baseline (236.514 us; speedup 1.0000x reference)
//
#include <hip/hip_runtime.h>
#include <hip/hip_bf16.h>

#define NROWS   16384
#define IN_DIM  1024
#define ENC_DIM 256
#define KCW     8192
#define NCB     32          // codeword col-blocks of 256

typedef __attribute__((ext_vector_type(8))) short short8v;
typedef __attribute__((ext_vector_type(4))) float f32x4;
typedef unsigned long long u64;
typedef unsigned int u32;

// ---------------------------------------------------------------------------
// helpers
// ---------------------------------------------------------------------------
__device__ __forceinline__ unsigned short f2bf_rne(float x) {
    unsigned u = __float_as_uint(x);
    unsigned r = (u + 0x7fffu + ((u >> 16) & 1u)) >> 16;
    return (unsigned short)r;
}
__device__ __forceinline__ float bf2f(unsigned short h) {
    return __uint_as_float(((unsigned)h) << 16);
}
__device__ __forceinline__ int lex_lt(float d, int i, float D, int I) {
    return (d < D) || (d == D && i < I);
}
__device__ __forceinline__ void t2mrg(u64& b1, u64& b2, u64 c1, u64 c2) {
    u64 hi = (b1 > c1) ? b1 : c1;
    u64 lo2 = (b2 < c2) ? b2 : c2;
    b1 = (b1 < c1) ? b1 : c1;
    b2 = (hi < lo2) ? hi : lo2;
}
__device__ __forceinline__ void gload16(const void* g, void* l) {
    __builtin_amdgcn_global_load_lds(
        (__attribute__((address_space(1))) void*)g,
        (__attribute__((address_space(3))) void*)l, 16, 0, 0);
}

// ---------------------------------------------------------------------------
// prep bodies (weights + codewords; cw split fuses the rownorm reduction)
// ---------------------------------------------------------------------------
template<int K>
__device__ __forceinline__ void tsplit_body(const float* __restrict__ W,
                                            unsigned short* __restrict__ Wt,
                                            int Ncols, int idx) {
    int n = idx / (K / 4), k4 = (idx % (K / 4)) * 4;
    float vx = W[(size_t)(k4 + 0) * Ncols + n];
    float vy = W[(size_t)(k4 + 1) * Ncols + n];
    float vz = W[(size_t)(k4 + 2) * Ncols + n];
    float vw = W[(size_t)(k4 + 3) * Ncols + n];
    ushort4 hi, lo;
    hi.x = f2bf_rne(vx); lo.x = f2bf_rne(vx - bf2f(hi.x));
    hi.y = f2bf_rne(vy); lo.y = f2bf_rne(vy - bf2f(hi.y));
    hi.z = f2bf_rne(vz); lo.z = f2bf_rne(vz - bf2f(hi.z));
    hi.w = f2bf_rne(vw); lo.w = f2bf_rne(vw - bf2f(hi.w));
    const int m = (n & 7) << 4;
    char* rp = (char*)(Wt + (size_t)n * (2 * K));
    int bh = k4 * 2, bl = (K + k4) * 2;
    *(ushort4*)(rp + ((bh & ~127) | ((bh & 127) ^ m))) = hi;
    *(ushort4*)(rp + ((bl & ~127) | ((bl & 127) ^ m))) = lo;
}

__global__ __launch_bounds__(256)
void prep_all(const float* __restrict__ ew1, const float* __restrict__ ew2,
              const float* __restrict__ dw1, const float* __restrict__ dw2,
              const float* __restrict__ cw,
              unsigned short* __restrict__ w1ts, unsigned short* __restrict__ ew2t,
              unsigned short* __restrict__ dw1t, unsigned short* __restrict__ dw2t,
              unsigned short* __restrict__ Be,   float* __restrict__ c2) {
    int idx = blockIdx.x * 256 + threadIdx.x;
    if (idx < 65536)        { tsplit_body<1024>(ew1, w1ts, 256, idx); }
    else if (idx < 81920)   { tsplit_body<256>(ew2, ew2t, 256, idx - 65536); }
    else if (idx < 98304)   { tsplit_body<256>(dw1, dw1t, 256, idx - 81920); }
    else if (idx < 163840)  { tsplit_body<256>(dw2, dw2t, 1024, idx - 98304); }
    else if (idx < 688128) {
        int e = idx - 163840;
        int row = e >> 6, kq = (e & 63) * 4;
        float4 v = ((const float4*)cw)[e];
        ushort4 hi, lo;
        hi.x = f2bf_rne(v.x); lo.x = f2bf_rne(v.x - bf2f(hi.x));
        hi.y = f2bf_rne(v.y); lo.y = f2bf_rne(v.y - bf2f(hi.y));
        hi.z = f2bf_rne(v.z); lo.z = f2bf_rne(v.z - bf2f(hi.z));
        hi.w = f2bf_rne(v.w); lo.w = f2bf_rne(v.w - bf2f(hi.w));
        const int m = (row & 7) << 4;
        char* rowp = (char*)(Be + (size_t)row * 512);
        int bh = kq * 2, bl = (256 + kq) * 2;
        *(ushort4*)(rowp + ((bh & ~127) | ((bh & 127) ^ m))) = hi;
        *(ushort4*)(rowp + ((bl & ~127) | ((bl & 127) ^ m))) = lo;
        float s = (v.x * v.x + v.y * v.y) + (v.z * v.z + v.w * v.w);
#pragma unroll
        for (int off = 1; off < 64; off <<= 1) s += __shfl_xor(s, off);
        if ((threadIdx.x & 63) == 0) c2[row] = s;
    }
}

// ---------------------------------------------------------------------------
// 512-thread (8-wave) split-bf16 MFMA GEMM body, LDS pool passed in
// (As[128][64] at +0, Bs[128][64] at +16384; 32 KB total).
// EPI: 1 = relu, C fp32 + Cs hi;  2 = relu, Cs hi+lo;  3 = no relu, C only.
// ---------------------------------------------------------------------------
struct MMP {
    const unsigned short* A;
    const unsigned short* Bt;
    const float* bias;
    float* C;
    unsigned short* Cs;
    int N, ars, brs, crs, KQ, EPI, gx;
};

__device__ void mm_device512(const MMP p, int bx, int by, int tid, char* lds) {
    unsigned short (*As)[64] = (unsigned short(*)[64])lds;
    unsigned short (*Bs)[64] = (unsigned short(*)[64])(lds + 16384);
    const int lane = tid & 63;
    const int wid = tid >> 6;
    const int wr = wid >> 2, wc = wid & 3;
    const int brow = by * 128;
    const int bcol = bx * 128;
    const int K = p.KQ * 64;

    f32x4 acc[4][2] = {};

    const int fr = tid >> 3;
    const int fk = (tid & 7) * 8;
    const int swz = (lane & 7) << 4;
    const int arow = wr * 64 + (lane & 15);
    const int brw  = wc * 32 + (lane & 15);
    const int klane = (lane >> 4) * 16;

    bool first = true;
#pragma unroll
    for (int term = 0; term < 3; ++term) {
        const int kaT = (term == 2) ? K : 0;
        const int kbT = (term == 1) ? K : 0;
        for (int kq = 0; kq < p.KQ; ++kq) {
            if (!first) __syncthreads();
            first = false;
            const int ka0 = kaT + kq * 64;
            const int kb0 = kbT + kq * 64;
#pragma unroll
            for (int l = 0; l < 2; ++l) {
                gload16(p.A  + (size_t)(brow + l * 64 + fr) * p.ars + ka0 + fk,
                        (char*)&As[0][0] + l * 8192 + tid * 16);
                gload16(p.Bt + (size_t)(bcol + l * 64 + fr) * p.brs + kb0 + fk,
                        (char*)&Bs[0][0] + l * 8192 + tid * 16);
            }
            __syncthreads();
#pragma unroll
            for (int kk = 0; kk < 2; ++kk) {
                const int kb = (kk * 64 + klane) ^ swz;
                short8v af[4], bfv[2];
#pragma unroll
                for (int mi = 0; mi < 4; mi++)
                    af[mi] = *(const short8v*)((const char*)&As[arow + mi * 16][0] + kb);
#pragma unroll
                for (int ni = 0; ni < 2; ni++)
                    bfv[ni] = *(const short8v*)((const char*)&Bs[brw + ni * 16][0] + kb);
#pragma unroll
                for (int mi = 0; mi < 4; mi++)
#pragma unroll
                    for (int ni = 0; ni < 2; ni++)
                        acc[mi][ni] = __builtin_amdgcn_mfma_f32_16x16x32_bf16(
                            af[mi], bfv[ni], acc[mi][ni], 0, 0, 0);
            }
        }
    }

#pragma unroll
    for (int mi = 0; mi < 4; mi++) {
#pragma unroll
        for (int q = 0; q < 4; q++) {
            int row = brow + wr * 64 + mi * 16 + (lane >> 4) * 4 + q;
            const int m = (row & 7) << 4;
            char* rp = (char*)(p.Cs + (size_t)row * p.crs);
#pragma unroll
            for (int ni = 0; ni < 2; ni++) {
                int col = bcol + wc * 32 + ni * 16 + (lane & 15);
                float v = acc[mi][ni][q] + p.bias[col];
                if (p.EPI != 3) v = fmaxf(v, 0.f);
                if (p.EPI & 1) p.C[(size_t)row * p.N + col] = v;
                if (p.EPI != 3) {
                    unsigned short hi = f2bf_rne(v);
                    int bh = col * 2;
                    *(unsigned short*)(rp + ((bh & ~127) | ((bh & 127) ^ m))) = hi;
                    if (p.EPI == 2) {
                        unsigned short lo = f2bf_rne(v - bf2f(hi));
                        int bl = (256 + col) * 2;
                        *(unsigned short*)(rp + ((bl & ~127) | ((bl & 127) ^ m))) = lo;
                    }
                }
            }
        }
    }
}

__global__ __launch_bounds__(512)
void mm_one(MMP p) {
    __shared__ __align__(16) char pool[32768];
    mm_device512(p, blockIdx.x % p.gx, blockIdx.x / p.gx, threadIdx.x, pool);
}

// ---------------------------------------------------------------------------
// enc1 (unchanged): single pass over x, 3 terms interleaved per k-step.
// ---------------------------------------------------------------------------
__global__ __launch_bounds__(512)
void enc1_fused(const float* __restrict__ x,
                const unsigned short* __restrict__ w1ts,
                const float* __restrict__ bias,
                unsigned short* __restrict__ Hs) {
    __shared__ __align__(16) unsigned short Ah[64][64];
    __shared__ __align__(16) unsigned short Al[64][64];
    __shared__ __align__(16) unsigned short Bh[256][64];
    __shared__ __align__(16) unsigned short Bl[256][64];
    const int tid = threadIdx.x;
    const int lane = tid & 63;
    const int wid = tid >> 6;
    const int wr = wid >> 2, wc = wid & 3;
    const int brow = blockIdx.x * 64;

    f32x4 acc[2][4] = {};

    const int fr = tid >> 3;
    const int fk = (tid & 7) * 8;
    const int swz = (lane & 7) << 4;
    const int arow = wr * 32 + (lane & 15);
    const int brw  = wc * 64 + (lane & 15);
    const int klane = (lane >> 4) * 16;
    const int aoff = fr * 128 + ((fk * 2) ^ ((fr & 7) << 4));

    float4 c0, c1, n0, n1;
    {
        const float* xp = x + (size_t)(brow + fr) * 1024 + fk;
        c0 = *(const float4*)xp; c1 = *(const float4*)(xp + 4);
    }

    for (int s = 0; s < 16; ++s) {
        const int k0 = s * 64;
        if (s) __syncthreads();
        {
            float vv[8] = { c0.x, c0.y, c0.z, c0.w, c1.x, c1.y, c1.z, c1.w };
            short8v uh, ul;
#pragma unroll
            for (int i = 0; i < 8; i++) {
                unsigned short h = f2bf_rne(vv[i]);
                uh[i] = (short)h;
                ul[i] = (short)f2bf_rne(vv[i] - bf2f(h));
            }
            *(short8v*)((char*)&Ah[0][0] + aoff) = uh;
            *(short8v*)((char*)&Al[0][0] + aoff) = ul;
        }
#pragma unroll
        for (int l = 0; l < 4; ++l) {
            gload16(w1ts + (size_t)(l * 64 + fr) * 2048 + k0 + fk,
                    (char*)&Bh[0][0] + l * 8192 + tid * 16);
            gload16(w1ts + (size_t)(l * 64 + fr) * 2048 + 1024 + k0 + fk,
                    (char*)&Bl[0][0] + l * 8192 + tid * 16);
        }
        if (s + 1 < 16) {
            const float* xp = x + (size_t)(brow + fr) * 1024 + k0 + 64 + fk;
            n0 = *(const float4*)xp; n1 = *(const float4*)(xp + 4);
        }
        __syncthreads();
#pragma unroll
        for (int kk = 0; kk < 2; ++kk) {
            const int kb = (kk * 64 + klane) ^ swz;
            short8v ah[2], al[2], bh[4], bl[4];
#pragma unroll
            for (int mi = 0; mi < 2; mi++) {
                ah[mi] = *(const short8v*)((const char*)&Ah[arow + mi * 16][0] + kb);
                al[mi] = *(const short8v*)((const char*)&Al[arow + mi * 16][0] + kb);
            }
#pragma unroll
            for (int ni = 0; ni < 4; ni++) {
                bh[ni] = *(const short8v*)((const char*)&Bh[brw + ni * 16][0] + kb);
                bl[ni] = *(const short8v*)((const char*)&Bl[brw + ni * 16][0] + kb);
            }
#pragma unroll
            for (int mi = 0; mi < 2; mi++)
#pragma unroll
                for (int ni = 0; ni < 4; ni++) {
                    acc[mi][ni] = __builtin_amdgcn_mfma_f32_16x16x32_bf16(
                        ah[mi], bh[ni], acc[mi][ni], 0, 0, 0);
                    acc[mi][ni] = __builtin_amdgcn_mfma_f32_16x16x32_bf16(
                        ah[mi], bl[ni], acc[mi][ni], 0, 0, 0);
                    acc[mi][ni] = __builtin_amdgcn_mfma_f32_16x16x32_bf16(
                        al[mi], bh[ni], acc[mi][ni], 0, 0, 0);
                }
        }
        c0 = n0; c1 = n1;
    }

#pragma unroll
    for (int mi = 0; mi < 2; mi++) {
#pragma unroll
        for (int q = 0; q < 4; q++) {
            int row = brow + wr * 32 + mi * 16 + (lane >> 4) * 4 + q;
            const int m = (row & 7) << 4;
            char* rp = (char*)(Hs + (size_t)row * 512);
#pragma unroll
            for (int ni = 0; ni < 4; ni++) {
                int col = wc * 64 + ni * 16 + (lane & 15);
                float v = fmaxf(acc[mi][ni][q] + bias[col], 0.f);
                unsigned short hi = f2bf_rne(v);
                unsigned short lo = f2bf_rne(v - bf2f(hi));
                int bh_ = col * 2, bl_ = (256 + col) * 2;
                *(unsigned short*)(rp + ((bh_ & ~127) | ((bh_ & 127) ^ m))) = hi;
                *(unsigned short*)(rp + ((bl_ & ~127) | ((bl_ & 127) ^ m))) = lo;
            }
        }
    }
}

// ---------------------------------------------------------------------------
// VQ MFMA kernel — ROUND-12 STRUCTURE RESTORED (2-barrier, 53 KB pool,
// ~3 blocks/CU): hi-only bf16 d2-key GEMM (K=256), 128x256 tile, 512
// threads, swapped-operand MFMA, u32-packed top-2. dec1 blocks appended.
// ---------------------------------------------------------------------------
__global__ __launch_bounds__(512)
void vq_mfma(const unsigned short* __restrict__ Ae,
             const unsigned short* __restrict__ Be,
             const float* __restrict__ c2,
             ulonglong2* __restrict__ part,
             MMP pd, int nvq) {
    __shared__ __align__(16) char pool[53248];
    if ((int)blockIdx.x >= nvq) {
        int b = blockIdx.x - nvq;
        mm_device512(pd, b % pd.gx, b / pd.gx, threadIdx.x, pool);
        return;
    }
    unsigned short (*As)[64] = (unsigned short(*)[64])pool;
    unsigned short (*Bs)[64] = (unsigned short(*)[64])(pool + 16384);
    u32* s1 = (u32*)(pool + 49152);
    u32* s2 = (u32*)(pool + 51200);

    const int tid  = threadIdx.x;
    const int lane = tid & 63;
    const int wid  = tid >> 6;
    const int wr   = wid >> 2;
    const int wc   = wid & 3;
    const int bid  = blockIdx.x;
    const int brow = (bid >> 5) * 128;
    const int bcol = (bid & 31) * 256;

    f32x4 acc[4][4] = {};

    const int fr = tid >> 3;
    const int fk = (tid & 7) * 8;
    const int swz   = (lane & 7) << 4;
    const int arow  = wr * 64 + (lane & 15);
    const int brw   = wc * 64 + (lane & 15);
    const int klane = (lane >> 4) * 16;

    for (int s = 0; s < 4; ++s) {
        const int k0 = s * 64;
        if (s) __syncthreads();
#pragma unroll
        for (int l = 0; l < 2; ++l)
            gload16(Ae + (size_t)(brow + l * 64 + fr) * 256 + k0 + fk,
                    (char*)&As[0][0] + l * 8192 + tid * 16);
#pragma unroll
        for (int l = 0; l < 4; ++l)
            gload16(Be + (size_t)(bcol + l * 64 + fr) * 512 + k0 + fk,
                    (char*)&Bs[0][0] + l * 8192 + tid * 16);
        __syncthreads();
#pragma unroll
        for (int kk = 0; kk < 2; ++kk) {
            const int kb = (kk * 64 + klane) ^ swz;
            short8v af[4], bfv[4];
#pragma unroll
            for (int mi = 0; mi < 4; mi++)
                af[mi] = *(const short8v*)((const char*)&As[arow + mi * 16][0] + kb);
#pragma unroll
            for (int ni = 0; ni < 4; ni++)
                bfv[ni] = *(const short8v*)((const char*)&Bs[brw + ni * 16][0] + kb);
#pragma unroll
            for (int mi = 0; mi < 4; mi++)
#pragma unroll
                for (int ni = 0; ni < 4; ni++)
                    acc[mi][ni] = __builtin_amdgcn_mfma_f32_16x16x32_bf16(
                        bfv[ni], af[mi], acc[mi][ni], 0, 0, 0);
        }
    }

    const int qrow = lane & 15;
    const int cq   = (lane >> 4) * 4;
    float4 c2q[4];
#pragma unroll
    for (int ni = 0; ni < 4; ni++)
        c2q[ni] = *(const float4*)&c2[bcol + wc * 64 + ni * 16 + cq];

#pragma unroll
    for (int mi = 0; mi < 4; mi++) {
        u32 b1 = 0xFFFFFFFFu, b2 = 0xFFFFFFFFu;
#pragma unroll
        for (int ni = 0; ni < 4; ni++) {
            const float* cp = (const float*)&c2q[ni];
#pragma unroll
            for (int r = 0; r < 4; r++) {
                float dk = fmaf(-2.0f, acc[mi][ni][r], cp[r]);
                dk = fmaxf(dk, 0.0f);
                u32 k = (__float_as_uint(dk) & ~255u)
                      | (u32)(wc * 64 + ni * 16 + cq + r);
                u32 mx = max(k, b1);
                b1 = min(k, b1);
                b2 = min(mx, b2);
            }
        }
#pragma unroll
        for (int off = 16; off < 64; off <<= 1) {
            u32 o1 = __shfl_xor(b1, off);
            u32 o2 = __shfl_xor(b2, off);
            u32 mx = max(b1, o1);
            b1 = min(b1, o1);
            b2 = min(min(b2, o2), mx);
        }
        if (lane < 16) {
            int rl = wr * 64 + mi * 16 + qrow;
            s1[rl * 4 + wc] = b1;
            s2[rl * 4 + wc] = b2;
        }
    }
    __syncthreads();
    if (tid < 128) {
        u32 b1 = s1[tid * 4 + 0], b2 = s2[tid * 4 + 0];
#pragma unroll
        for (int w = 1; w < 4; w++) {
            u32 c1 = s1[tid * 4 + w], cc2 = s2[tid * 4 + w];
            u32 mx = max(b1, c1);
            b1 = min(b1, c1);
            b2 = min(min(b2, cc2), mx);
        }
        ulonglong2 pk;
        pk.x = ((u64)b1 << 32) | (u32)(bcol + (b1 & 255u));
        pk.y = ((u64)b2 << 32) | (u32)(bcol + (b2 & 255u));
        part[(size_t)(brow + tid) * NCB + (bid & 31)] = pk;
    }
}

// ---------------------------------------------------------------------------
// combine: 8 rows/block, global approx top-2 -> exact fp32 rescore, fused
// outQ gather (lanes already hold w1/w2).
// ---------------------------------------------------------------------------
__global__ __launch_bounds__(512)
void vq_combine(const ulonglong2* __restrict__ part,
                const float* __restrict__ enc,
                const float* __restrict__ cw,
                const float* __restrict__ c2,
                float* __restrict__ outIdx,
                float* __restrict__ outDist,
                int* __restrict__ idx32,
                float* __restrict__ outQ) {
    const int row  = blockIdx.x * 8 + (threadIdx.x >> 6);
    const int lane = threadIdx.x & 63;

    u64 b1 = ~0ull, b2 = ~0ull;
    if (lane < NCB) {
        ulonglong2 pk = part[(size_t)row * NCB + lane];
        b1 = pk.x; b2 = pk.y;
    }
#pragma unroll
    for (int off = 1; off < 64; off <<= 1) {
        u64 c1 = __shfl_xor(b1, off);
        u64 cc2 = __shfl_xor(b2, off);
        t2mrg(b1, b2, c1, cc2);
    }
    int j1 = (int)(b1 & 0xffffffffu);
    int j2 = (int)(b2 & 0xffffffffu);

    float4 e4 = ((const float4*)(enc + (size_t)row * 256))[lane];
    float4 w1 = ((const float4*)(cw + (size_t)j1 * 256))[lane];
    float4 w2 = ((const float4*)(cw + (size_t)j2 * 256))[lane];
    float s1 = fmaf(e4.x, w1.x, fmaf(e4.y, w1.y, fmaf(e4.z, w1.z, e4.w * w1.w)));
    float s2 = fmaf(e4.x, w2.x, fmaf(e4.y, w2.y, fmaf(e4.z, w2.z, e4.w * w2.w)));
    float sx = (e4.x * e4.x + e4.y * e4.y) + (e4.z * e4.z + e4.w * e4.w);
#pragma unroll
    for (int off = 1; off < 64; off <<= 1) {
        s1 += __shfl_xor(s1, off);
        s2 += __shfl_xor(s2, off);
        sx += __shfl_xor(sx, off);
    }
    float d1 = sqrtf(fmaxf(sx + c2[j1] - 2.0f * s1, 0.f));
    float d2 = sqrtf(fmaxf(sx + c2[j2] - 2.0f * s2, 0.f));
    float bd; int bi;
    if (lex_lt(d1, j1, d2, j2)) { bd = d1; bi = j1; }
    else                        { bd = d2; bi = j2; }
    float4 wq = (bi == j1) ? w1 : w2;
    ((float4*)(outQ + (size_t)row * ENC_DIM))[lane] = wq;
    if (lane == 0) {
        outIdx[row]  = (float)bi;
        outDist[row] = bd;
        idx32[row]   = bi;
    }
}

// ---------------------------------------------------------------------------
// dec2_gather: outRec[row] = Gs[idx32[row]] @ dw2t + db2  (no relu, fp32 out)
// M=16384 gathered rows, N=1024, K=256 (3-term split). A is reg-staged from
// Gs[j] with source-side (j&7) un-swizzle and dest-side (fr&7) re-swizzle;
// B via gload16 from pre-split dw2t. Row-wise math identical to computing
// rec per-codeword then gathering -> bit-identical outRec.
// ---------------------------------------------------------------------------
__global__ __launch_bounds__(512)
void dec2_gather(const unsigned short* __restrict__ Gs,
                 const unsigned short* __restrict__ dw2t,
                 const float* __restrict__ bias,
                 const int* __restrict__ idx32,
                 float* __restrict__ outRec) {
    __shared__ __align__(16) unsigned short As[128][64];
    __shared__ __align__(16) unsigned short Bs[128][64];
    const int tid = threadIdx.x;
    const int lane = tid & 63;
    const int wid = tid >> 6;
    const int wr = wid >> 2, wc = wid & 3;
    const int bx = blockIdx.x & 7, by = blockIdx.x >> 3;
    const int brow = by * 128;
    const int bcol = bx * 128;

    f32x4 acc[4][2] = {};

    const int fr = tid >> 3;
    const int fk = (tid & 7) * 8;
    const int swz = (lane & 7) << 4;
    const int arow = wr * 64 + (lane & 15);
    const int brw  = wc * 32 + (lane & 15);
    const int klane = (lane >> 4) * 16;

    const int j0 = idx32[brow + fr];
    const int j1r = idx32[brow + 64 + fr];
    const int aoff0 = fr * 128 + ((fk * 2) ^ ((fr & 7) << 4));

    bool first = true;
#pragma unroll
    for (int term = 0; term < 3; ++term) {
        const int kaT = (term == 2) ? 256 : 0;
        const int kbT = (term == 1) ? 256 : 0;
        for (int kq = 0; kq < 4; ++kq) {
            if (!first) __syncthreads();
            first = false;
            const int ka0 = kaT + kq * 64;
            const int kb0 = kbT + kq * 64;
            // A: reg-staged gather from Gs[j], swizzle-corrected
            {
                const char* src0 = (const char*)Gs + (size_t)j0 * 1024
                                 + ka0 * 2 + ((fk * 2) ^ ((j0 & 7) << 4));
                const char* src1 = (const char*)Gs + (size_t)j1r * 1024
                                 + ka0 * 2 + ((fk * 2) ^ ((j1r & 7) << 4));
                short8v v0 = *(const short8v*)src0;
                short8v v1 = *(const short8v*)src1;
                *(short8v*)((char*)&As[0][0] + aoff0) = v0;
                *(short8v*)((char*)&As[0][0] + 8192 + aoff0) = v1;
            }
            // B: async global->LDS from pre-split dw2t
#pragma unroll
            for (int l = 0; l < 2; ++l)
                gload16(dw2t + (size_t)(bcol + l * 64 + fr) * 512 + kb0 + fk,
                        (char*)&Bs[0][0] + l * 8192 + tid * 16);
            __syncthreads();
#pragma unroll
            for (int kk = 0; kk < 2; ++kk) {
                const int kb = (kk * 64 + klane) ^ swz;
                short8v af[4], bfv[2];
#pragma unroll
                for (int mi = 0; mi < 4; mi++)
                    af[mi] = *(const short8v*)((const char*)&As[arow + mi * 16][0] + kb);
#pragma unroll
                for (int ni = 0; ni < 2; ni++)
                    bfv[ni] = *(const short8v*)((const char*)&Bs[brw + ni * 16][0] + kb);
#pragma unroll
                for (int mi = 0; mi < 4; mi++)
#pragma unroll
                    for (int ni = 0; ni < 2; ni++)
                        acc[mi][ni] = __builtin_amdgcn_mfma_f32_16x16x32_bf16(
                            af[mi], bfv[ni], acc[mi][ni], 0, 0, 0);
            }
        }
    }

#pragma unroll
    for (int mi = 0; mi < 4; mi++) {
#pragma unroll
        for (int q = 0; q < 4; q++) {
            int row = brow + wr * 64 + mi * 16 + (lane >> 4) * 4 + q;
#pragma unroll
            for (int ni = 0; ni < 2; ni++) {
                int col = bcol + wc * 32 + ni * 16 + (lane & 15);
                outRec[(size_t)row * 1024 + col] = acc[mi][ni][q] + bias[col];
            }
        }
    }
}

extern "C" void kernel_launch(void* const* d_in, const int* in_sizes, int n_in,
                              void* d_out, int out_size, void* d_ws, size_t ws_size,
                              hipStream_t stream) {
    const float* x   = (const float*)d_in[0];
    const float* ew1 = (const float*)d_in[1];
    const float* eb1 = (const float*)d_in[2];
    const float* ew2 = (const float*)d_in[3];
    const float* eb2 = (const float*)d_in[4];
    const float* cw  = (const float*)d_in[5];
    const float* dw1 = (const float*)d_in[6];
    const float* db1 = (const float*)d_in[7];
    const float* dw2 = (const float*)d_in[8];
    const float* db2 = (const float*)d_in[9];
    float* out = (float*)d_out;
    float* ws  = (float*)d_ws;

    float* outIdx  = out;
    float* outDist = out + NROWS;
    float* outRec  = out + 2 * NROWS;
    float* outQ    = out + 2 * NROWS + (size_t)NROWS * IN_DIM;

    // layout (~21.7M floats). liveness: Hs (enc1->enc2) aliased by part
    // (vq+); Gs live dec1->dec2_gather; serial-launch ordered.
    float*          enc     = ws;                               // [0, 4.19M)
    unsigned short* Ae      = (unsigned short*)(ws + 4194304);  // [., 6.29M)
    unsigned short* Gs      = (unsigned short*)(ws + 6291456);  // [., 8.39M)
    unsigned short* Hs      = (unsigned short*)(ws + 8388608);  // [., 12.58M)
    ulonglong2*     part    = (ulonglong2*)(ws + 8388608);      // [., 10.49M)
    unsigned short* Be      = (unsigned short*)(ws + 18874368); // [., 20.97M)
    unsigned short* w1ts    = (unsigned short*)(ws + 20971520); // 1 MB
    unsigned short* ew2t    = (unsigned short*)(ws + 21233664);
    unsigned short* dw1t    = (unsigned short*)(ws + 21299200);
    unsigned short* dw2t    = (unsigned short*)(ws + 21364736);
    float*          c2      = ws + 21626880;
    int*            idx32   = (int*)(ws + 21635072);

    MMP p_enc2 = { Hs, ew2t, eb2, enc, Ae, 256, 512, 512, 256, 4, 1, 2 };
    MMP p_dec1 = { Be, dw1t, db1, nullptr, Gs, 256, 512, 512, 512, 4, 2, 2 };

    prep_all<<<2688, 256, 0, stream>>>(ew1, ew2, dw1, dw2, cw,
                                       w1ts, ew2t, dw1t, dw2t, Be, c2);
    enc1_fused<<<256, 512, 0, stream>>>(x, w1ts, eb1, Hs);
    mm_one<<<256, 512, 0, stream>>>(p_enc2);
    vq_mfma<<<4096 + 128, 512, 0, stream>>>(Ae, Be, c2, part, p_dec1, 4096);
    vq_combine<<<NROWS / 8, 512, 0, stream>>>(part, enc, cw, c2,
                                              outIdx, outDist, idx32, outQ);
    dec2_gather<<<1024, 512, 0, stream>>>(Gs, dw2t, db2, idx32, outRec);
}

// Round 15
// 190.813 us; speedup vs baseline: 1.2395x; 1.2395x over previous
//
#include <hip/hip_runtime.h>
#include <hip/hip_bf16.h>

#define NROWS   16384
#define IN_DIM  1024
#define ENC_DIM 256
#define KCW     8192
#define NCB     32          // codeword col-blocks of 256

typedef __attribute__((ext_vector_type(8))) short short8v;
typedef __attribute__((ext_vector_type(4))) float f32x4;
typedef unsigned long long u64;
typedef unsigned int u32;

// ---------------------------------------------------------------------------
// helpers
// ---------------------------------------------------------------------------
__device__ __forceinline__ unsigned short f2bf_rne(float x) {
    unsigned u = __float_as_uint(x);
    unsigned r = (u + 0x7fffu + ((u >> 16) & 1u)) >> 16;
    return (unsigned short)r;
}
__device__ __forceinline__ float bf2f(unsigned short h) {
    return __uint_as_float(((unsigned)h) << 16);
}
__device__ __forceinline__ int lex_lt(float d, int i, float D, int I) {
    return (d < D) || (d == D && i < I);
}
__device__ __forceinline__ void t2mrg(u64& b1, u64& b2, u64 c1, u64 c2) {
    u64 hi = (b1 > c1) ? b1 : c1;
    u64 lo2 = (b2 < c2) ? b2 : c2;
    b1 = (b1 < c1) ? b1 : c1;
    b2 = (hi < lo2) ? hi : lo2;
}
__device__ __forceinline__ void gload16(const void* g, void* l) {
    __builtin_amdgcn_global_load_lds(
        (__attribute__((address_space(1))) void*)g,
        (__attribute__((address_space(3))) void*)l, 16, 0, 0);
}

// ---------------------------------------------------------------------------
// prep bodies (weights + codewords; cw split fuses the rownorm reduction)
// ---------------------------------------------------------------------------
template<int K>
__device__ __forceinline__ void tsplit_body(const float* __restrict__ W,
                                            unsigned short* __restrict__ Wt,
                                            int Ncols, int idx) {
    int n = idx / (K / 4), k4 = (idx % (K / 4)) * 4;
    float vx = W[(size_t)(k4 + 0) * Ncols + n];
    float vy = W[(size_t)(k4 + 1) * Ncols + n];
    float vz = W[(size_t)(k4 + 2) * Ncols + n];
    float vw = W[(size_t)(k4 + 3) * Ncols + n];
    ushort4 hi, lo;
    hi.x = f2bf_rne(vx); lo.x = f2bf_rne(vx - bf2f(hi.x));
    hi.y = f2bf_rne(vy); lo.y = f2bf_rne(vy - bf2f(hi.y));
    hi.z = f2bf_rne(vz); lo.z = f2bf_rne(vz - bf2f(hi.z));
    hi.w = f2bf_rne(vw); lo.w = f2bf_rne(vw - bf2f(hi.w));
    const int m = (n & 7) << 4;
    char* rp = (char*)(Wt + (size_t)n * (2 * K));
    int bh = k4 * 2, bl = (K + k4) * 2;
    *(ushort4*)(rp + ((bh & ~127) | ((bh & 127) ^ m))) = hi;
    *(ushort4*)(rp + ((bl & ~127) | ((bl & 127) ^ m))) = lo;
}

__global__ __launch_bounds__(256)
void prep_all(const float* __restrict__ ew1, const float* __restrict__ ew2,
              const float* __restrict__ dw1, const float* __restrict__ dw2,
              const float* __restrict__ cw,
              unsigned short* __restrict__ w1ts, unsigned short* __restrict__ ew2t,
              unsigned short* __restrict__ dw1t, unsigned short* __restrict__ dw2t,
              unsigned short* __restrict__ Be,   float* __restrict__ c2) {
    int idx = blockIdx.x * 256 + threadIdx.x;
    if (idx < 65536)        { tsplit_body<1024>(ew1, w1ts, 256, idx); }
    else if (idx < 81920)   { tsplit_body<256>(ew2, ew2t, 256, idx - 65536); }
    else if (idx < 98304)   { tsplit_body<256>(dw1, dw1t, 256, idx - 81920); }
    else if (idx < 163840)  { tsplit_body<256>(dw2, dw2t, 1024, idx - 98304); }
    else if (idx < 688128) {
        int e = idx - 163840;
        int row = e >> 6, kq = (e & 63) * 4;
        float4 v = ((const float4*)cw)[e];
        ushort4 hi, lo;
        hi.x = f2bf_rne(v.x); lo.x = f2bf_rne(v.x - bf2f(hi.x));
        hi.y = f2bf_rne(v.y); lo.y = f2bf_rne(v.y - bf2f(hi.y));
        hi.z = f2bf_rne(v.z); lo.z = f2bf_rne(v.z - bf2f(hi.z));
        hi.w = f2bf_rne(v.w); lo.w = f2bf_rne(v.w - bf2f(hi.w));
        const int m = (row & 7) << 4;
        char* rowp = (char*)(Be + (size_t)row * 512);
        int bh = kq * 2, bl = (256 + kq) * 2;
        *(ushort4*)(rowp + ((bh & ~127) | ((bh & 127) ^ m))) = hi;
        *(ushort4*)(rowp + ((bl & ~127) | ((bl & 127) ^ m))) = lo;
        float s = (v.x * v.x + v.y * v.y) + (v.z * v.z + v.w * v.w);
#pragma unroll
        for (int off = 1; off < 64; off <<= 1) s += __shfl_xor(s, off);
        if ((threadIdx.x & 63) == 0) c2[row] = s;
    }
}

// ---------------------------------------------------------------------------
// 512-thread (8-wave) split-bf16 MFMA GEMM body, LDS pool passed in.
// EPI: 1 = relu, C fp32 + Cs hi;  2 = relu, Cs hi+lo;  3 = no relu, C only.
// ---------------------------------------------------------------------------
struct MMP {
    const unsigned short* A;
    const unsigned short* Bt;
    const float* bias;
    float* C;
    unsigned short* Cs;
    int N, ars, brs, crs, KQ, EPI, gx;
};

__device__ void mm_device512(const MMP p, int bx, int by, int tid, char* lds) {
    unsigned short (*As)[64] = (unsigned short(*)[64])lds;
    unsigned short (*Bs)[64] = (unsigned short(*)[64])(lds + 16384);
    const int lane = tid & 63;
    const int wid = tid >> 6;
    const int wr = wid >> 2, wc = wid & 3;
    const int brow = by * 128;
    const int bcol = bx * 128;
    const int K = p.KQ * 64;

    f32x4 acc[4][2] = {};

    const int fr = tid >> 3;
    const int fk = (tid & 7) * 8;
    const int swz = (lane & 7) << 4;
    const int arow = wr * 64 + (lane & 15);
    const int brw  = wc * 32 + (lane & 15);
    const int klane = (lane >> 4) * 16;

    bool first = true;
#pragma unroll
    for (int term = 0; term < 3; ++term) {
        const int kaT = (term == 2) ? K : 0;
        const int kbT = (term == 1) ? K : 0;
        for (int kq = 0; kq < p.KQ; ++kq) {
            if (!first) __syncthreads();
            first = false;
            const int ka0 = kaT + kq * 64;
            const int kb0 = kbT + kq * 64;
#pragma unroll
            for (int l = 0; l < 2; ++l) {
                gload16(p.A  + (size_t)(brow + l * 64 + fr) * p.ars + ka0 + fk,
                        (char*)&As[0][0] + l * 8192 + tid * 16);
                gload16(p.Bt + (size_t)(bcol + l * 64 + fr) * p.brs + kb0 + fk,
                        (char*)&Bs[0][0] + l * 8192 + tid * 16);
            }
            __syncthreads();
#pragma unroll
            for (int kk = 0; kk < 2; ++kk) {
                const int kb = (kk * 64 + klane) ^ swz;
                short8v af[4], bfv[2];
#pragma unroll
                for (int mi = 0; mi < 4; mi++)
                    af[mi] = *(const short8v*)((const char*)&As[arow + mi * 16][0] + kb);
#pragma unroll
                for (int ni = 0; ni < 2; ni++)
                    bfv[ni] = *(const short8v*)((const char*)&Bs[brw + ni * 16][0] + kb);
#pragma unroll
                for (int mi = 0; mi < 4; mi++)
#pragma unroll
                    for (int ni = 0; ni < 2; ni++)
                        acc[mi][ni] = __builtin_amdgcn_mfma_f32_16x16x32_bf16(
                            af[mi], bfv[ni], acc[mi][ni], 0, 0, 0);
            }
        }
    }

#pragma unroll
    for (int mi = 0; mi < 4; mi++) {
#pragma unroll
        for (int q = 0; q < 4; q++) {
            int row = brow + wr * 64 + mi * 16 + (lane >> 4) * 4 + q;
            const int m = (row & 7) << 4;
            char* rp = (char*)(p.Cs + (size_t)row * p.crs);
#pragma unroll
            for (int ni = 0; ni < 2; ni++) {
                int col = bcol + wc * 32 + ni * 16 + (lane & 15);
                float v = acc[mi][ni][q] + p.bias[col];
                if (p.EPI != 3) v = fmaxf(v, 0.f);
                if (p.EPI & 1) p.C[(size_t)row * p.N + col] = v;
                if (p.EPI != 3) {
                    unsigned short hi = f2bf_rne(v);
                    int bh = col * 2;
                    *(unsigned short*)(rp + ((bh & ~127) | ((bh & 127) ^ m))) = hi;
                    if (p.EPI == 2) {
                        unsigned short lo = f2bf_rne(v - bf2f(hi));
                        int bl = (256 + col) * 2;
                        *(unsigned short*)(rp + ((bl & ~127) | ((bl & 127) ^ m))) = lo;
                    }
                }
            }
        }
    }
}

__global__ __launch_bounds__(512)
void mm_pair(MMP p0, MMP p1, int n0) {
    __shared__ __align__(16) char pool[32768];
    if ((int)blockIdx.x < n0) {
        mm_device512(p0, blockIdx.x % p0.gx, blockIdx.x / p0.gx, threadIdx.x, pool);
    } else {
        int b = blockIdx.x - n0;
        mm_device512(p1, b % p1.gx, b / p1.gx, threadIdx.x, pool);
    }
}

// ---------------------------------------------------------------------------
// enc1 (unchanged): single pass over x, 3 terms interleaved per k-step.
// ---------------------------------------------------------------------------
__global__ __launch_bounds__(512)
void enc1_fused(const float* __restrict__ x,
                const unsigned short* __restrict__ w1ts,
                const float* __restrict__ bias,
                unsigned short* __restrict__ Hs) {
    __shared__ __align__(16) unsigned short Ah[64][64];
    __shared__ __align__(16) unsigned short Al[64][64];
    __shared__ __align__(16) unsigned short Bh[256][64];
    __shared__ __align__(16) unsigned short Bl[256][64];
    const int tid = threadIdx.x;
    const int lane = tid & 63;
    const int wid = tid >> 6;
    const int wr = wid >> 2, wc = wid & 3;
    const int brow = blockIdx.x * 64;

    f32x4 acc[2][4] = {};

    const int fr = tid >> 3;
    const int fk = (tid & 7) * 8;
    const int swz = (lane & 7) << 4;
    const int arow = wr * 32 + (lane & 15);
    const int brw  = wc * 64 + (lane & 15);
    const int klane = (lane >> 4) * 16;
    const int aoff = fr * 128 + ((fk * 2) ^ ((fr & 7) << 4));

    float4 c0, c1, n0, n1;
    {
        const float* xp = x + (size_t)(brow + fr) * 1024 + fk;
        c0 = *(const float4*)xp; c1 = *(const float4*)(xp + 4);
    }

    for (int s = 0; s < 16; ++s) {
        const int k0 = s * 64;
        if (s) __syncthreads();
        {
            float vv[8] = { c0.x, c0.y, c0.z, c0.w, c1.x, c1.y, c1.z, c1.w };
            short8v uh, ul;
#pragma unroll
            for (int i = 0; i < 8; i++) {
                unsigned short h = f2bf_rne(vv[i]);
                uh[i] = (short)h;
                ul[i] = (short)f2bf_rne(vv[i] - bf2f(h));
            }
            *(short8v*)((char*)&Ah[0][0] + aoff) = uh;
            *(short8v*)((char*)&Al[0][0] + aoff) = ul;
        }
#pragma unroll
        for (int l = 0; l < 4; ++l) {
            gload16(w1ts + (size_t)(l * 64 + fr) * 2048 + k0 + fk,
                    (char*)&Bh[0][0] + l * 8192 + tid * 16);
            gload16(w1ts + (size_t)(l * 64 + fr) * 2048 + 1024 + k0 + fk,
                    (char*)&Bl[0][0] + l * 8192 + tid * 16);
        }
        if (s + 1 < 16) {
            const float* xp = x + (size_t)(brow + fr) * 1024 + k0 + 64 + fk;
            n0 = *(const float4*)xp; n1 = *(const float4*)(xp + 4);
        }
        __syncthreads();
#pragma unroll
        for (int kk = 0; kk < 2; ++kk) {
            const int kb = (kk * 64 + klane) ^ swz;
            short8v ah[2], al[2], bh[4], bl[4];
#pragma unroll
            for (int mi = 0; mi < 2; mi++) {
                ah[mi] = *(const short8v*)((const char*)&Ah[arow + mi * 16][0] + kb);
                al[mi] = *(const short8v*)((const char*)&Al[arow + mi * 16][0] + kb);
            }
#pragma unroll
            for (int ni = 0; ni < 4; ni++) {
                bh[ni] = *(const short8v*)((const char*)&Bh[brw + ni * 16][0] + kb);
                bl[ni] = *(const short8v*)((const char*)&Bl[brw + ni * 16][0] + kb);
            }
#pragma unroll
            for (int mi = 0; mi < 2; mi++)
#pragma unroll
                for (int ni = 0; ni < 4; ni++) {
                    acc[mi][ni] = __builtin_amdgcn_mfma_f32_16x16x32_bf16(
                        ah[mi], bh[ni], acc[mi][ni], 0, 0, 0);
                    acc[mi][ni] = __builtin_amdgcn_mfma_f32_16x16x32_bf16(
                        ah[mi], bl[ni], acc[mi][ni], 0, 0, 0);
                    acc[mi][ni] = __builtin_amdgcn_mfma_f32_16x16x32_bf16(
                        al[mi], bh[ni], acc[mi][ni], 0, 0, 0);
                }
        }
        c0 = n0; c1 = n1;
    }

#pragma unroll
    for (int mi = 0; mi < 2; mi++) {
#pragma unroll
        for (int q = 0; q < 4; q++) {
            int row = brow + wr * 32 + mi * 16 + (lane >> 4) * 4 + q;
            const int m = (row & 7) << 4;
            char* rp = (char*)(Hs + (size_t)row * 512);
#pragma unroll
            for (int ni = 0; ni < 4; ni++) {
                int col = wc * 64 + ni * 16 + (lane & 15);
                float v = fmaxf(acc[mi][ni][q] + bias[col], 0.f);
                unsigned short hi = f2bf_rne(v);
                unsigned short lo = f2bf_rne(v - bf2f(hi));
                int bh_ = col * 2, bl_ = (256 + col) * 2;
                *(unsigned short*)(rp + ((bh_ & ~127) | ((bh_ & 127) ^ m))) = hi;
                *(unsigned short*)(rp + ((bl_ & ~127) | ((bl_ & 127) ^ m))) = lo;
            }
        }
    }
}

// ---------------------------------------------------------------------------
// VQ MFMA kernel — STANDALONE round-12 binary restored (no fused tail, no
// struct args -> VGPR 64, 3 blocks/CU): hi-only bf16 d2-key GEMM (K=256),
// 128x256 tile, 512 threads, swapped-operand MFMA, u32-packed top-2.
// ---------------------------------------------------------------------------
__global__ __launch_bounds__(512)
void vq_mfma(const unsigned short* __restrict__ Ae,
             const unsigned short* __restrict__ Be,
             const float* __restrict__ c2,
             ulonglong2* __restrict__ part) {
    __shared__ __align__(16) unsigned short As[128][64];
    __shared__ __align__(16) unsigned short Bs[256][64];
    __shared__ u32 s1[128][4];
    __shared__ u32 s2[128][4];

    const int tid  = threadIdx.x;
    const int lane = tid & 63;
    const int wid  = tid >> 6;
    const int wr   = wid >> 2;
    const int wc   = wid & 3;
    const int brow = blockIdx.y * 128;
    const int bcol = blockIdx.x * 256;

    f32x4 acc[4][4] = {};

    const int fr = tid >> 3;
    const int fk = (tid & 7) * 8;
    const int swz   = (lane & 7) << 4;
    const int arow  = wr * 64 + (lane & 15);
    const int brw   = wc * 64 + (lane & 15);
    const int klane = (lane >> 4) * 16;

    for (int s = 0; s < 4; ++s) {
        const int k0 = s * 64;
        if (s) __syncthreads();
#pragma unroll
        for (int l = 0; l < 2; ++l)
            gload16(Ae + (size_t)(brow + l * 64 + fr) * 256 + k0 + fk,
                    (char*)&As[0][0] + l * 8192 + tid * 16);
#pragma unroll
        for (int l = 0; l < 4; ++l)
            gload16(Be + (size_t)(bcol + l * 64 + fr) * 512 + k0 + fk,
                    (char*)&Bs[0][0] + l * 8192 + tid * 16);
        __syncthreads();
#pragma unroll
        for (int kk = 0; kk < 2; ++kk) {
            const int kb = (kk * 64 + klane) ^ swz;
            short8v af[4], bfv[4];
#pragma unroll
            for (int mi = 0; mi < 4; mi++)
                af[mi] = *(const short8v*)((const char*)&As[arow + mi * 16][0] + kb);
#pragma unroll
            for (int ni = 0; ni < 4; ni++)
                bfv[ni] = *(const short8v*)((const char*)&Bs[brw + ni * 16][0] + kb);
#pragma unroll
            for (int mi = 0; mi < 4; mi++)
#pragma unroll
                for (int ni = 0; ni < 4; ni++)
                    acc[mi][ni] = __builtin_amdgcn_mfma_f32_16x16x32_bf16(
                        bfv[ni], af[mi], acc[mi][ni], 0, 0, 0);
        }
    }

    const int qrow = lane & 15;
    const int cq   = (lane >> 4) * 4;
    float4 c2q[4];
#pragma unroll
    for (int ni = 0; ni < 4; ni++)
        c2q[ni] = *(const float4*)&c2[bcol + wc * 64 + ni * 16 + cq];

#pragma unroll
    for (int mi = 0; mi < 4; mi++) {
        u32 b1 = 0xFFFFFFFFu, b2 = 0xFFFFFFFFu;
#pragma unroll
        for (int ni = 0; ni < 4; ni++) {
            const float* cp = (const float*)&c2q[ni];
#pragma unroll
            for (int r = 0; r < 4; r++) {
                float dk = fmaf(-2.0f, acc[mi][ni][r], cp[r]);
                dk = fmaxf(dk, 0.0f);
                u32 k = (__float_as_uint(dk) & ~255u)
                      | (u32)(wc * 64 + ni * 16 + cq + r);
                u32 mx = max(k, b1);
                b1 = min(k, b1);
                b2 = min(mx, b2);
            }
        }
#pragma unroll
        for (int off = 16; off < 64; off <<= 1) {
            u32 o1 = __shfl_xor(b1, off);
            u32 o2 = __shfl_xor(b2, off);
            u32 mx = max(b1, o1);
            b1 = min(b1, o1);
            b2 = min(min(b2, o2), mx);
        }
        if (lane < 16) {
            int rl = wr * 64 + mi * 16 + qrow;
            s1[rl][wc] = b1;
            s2[rl][wc] = b2;
        }
    }
    __syncthreads();
    if (tid < 128) {
        u32 b1 = s1[tid][0], b2 = s2[tid][0];
#pragma unroll
        for (int w = 1; w < 4; w++) {
            u32 c1 = s1[tid][w], cc2 = s2[tid][w];
            u32 mx = max(b1, c1);
            b1 = min(b1, c1);
            b2 = min(min(b2, cc2), mx);
        }
        ulonglong2 pk;
        pk.x = ((u64)b1 << 32) | (u32)(bcol + (b1 & 255u));
        pk.y = ((u64)b2 << 32) | (u32)(bcol + (b2 & 255u));
        part[(size_t)(brow + tid) * NCB + blockIdx.x] = pk;
    }
}

// ---------------------------------------------------------------------------
// combine: 8 rows/block, global approx top-2 -> exact fp32 rescore, fused
// outQ gather (lanes already hold w1/w2).
// ---------------------------------------------------------------------------
__global__ __launch_bounds__(512)
void vq_combine(const ulonglong2* __restrict__ part,
                const float* __restrict__ enc,
                const float* __restrict__ cw,
                const float* __restrict__ c2,
                float* __restrict__ outIdx,
                float* __restrict__ outDist,
                int* __restrict__ idx32,
                float* __restrict__ outQ) {
    const int row  = blockIdx.x * 8 + (threadIdx.x >> 6);
    const int lane = threadIdx.x & 63;

    u64 b1 = ~0ull, b2 = ~0ull;
    if (lane < NCB) {
        ulonglong2 pk = part[(size_t)row * NCB + lane];
        b1 = pk.x; b2 = pk.y;
    }
#pragma unroll
    for (int off = 1; off < 64; off <<= 1) {
        u64 c1 = __shfl_xor(b1, off);
        u64 cc2 = __shfl_xor(b2, off);
        t2mrg(b1, b2, c1, cc2);
    }
    int j1 = (int)(b1 & 0xffffffffu);
    int j2 = (int)(b2 & 0xffffffffu);

    float4 e4 = ((const float4*)(enc + (size_t)row * 256))[lane];
    float4 w1 = ((const float4*)(cw + (size_t)j1 * 256))[lane];
    float4 w2 = ((const float4*)(cw + (size_t)j2 * 256))[lane];
    float s1 = fmaf(e4.x, w1.x, fmaf(e4.y, w1.y, fmaf(e4.z, w1.z, e4.w * w1.w)));
    float s2 = fmaf(e4.x, w2.x, fmaf(e4.y, w2.y, fmaf(e4.z, w2.z, e4.w * w2.w)));
    float sx = (e4.x * e4.x + e4.y * e4.y) + (e4.z * e4.z + e4.w * e4.w);
#pragma unroll
    for (int off = 1; off < 64; off <<= 1) {
        s1 += __shfl_xor(s1, off);
        s2 += __shfl_xor(s2, off);
        sx += __shfl_xor(sx, off);
    }
    float d1 = sqrtf(fmaxf(sx + c2[j1] - 2.0f * s1, 0.f));
    float d2 = sqrtf(fmaxf(sx + c2[j2] - 2.0f * s2, 0.f));
    float bd; int bi;
    if (lex_lt(d1, j1, d2, j2)) { bd = d1; bi = j1; }
    else                        { bd = d2; bi = j2; }
    float4 wq = (bi == j1) ? w1 : w2;
    ((float4*)(outQ + (size_t)row * ENC_DIM))[lane] = wq;
    if (lane == 0) {
        outIdx[row]  = (float)bi;
        outDist[row] = bd;
        idx32[row]   = bi;
    }
}

// ---------------------------------------------------------------------------
// dec2_gather: outRec[row] = Gs[idx32[row]] @ dw2t + db2  (no relu, fp32 out)
// A reg-staged from Gs[j] with source-side (j&7) un-swizzle + dest (fr&7)
// re-swizzle; B via gload16 from dw2t. Bit-identical to compute-then-gather.
// ---------------------------------------------------------------------------
__global__ __launch_bounds__(512)
void dec2_gather(const unsigned short* __restrict__ Gs,
                 const unsigned short* __restrict__ dw2t,
                 const float* __restrict__ bias,
                 const int* __restrict__ idx32,
                 float* __restrict__ outRec) {
    __shared__ __align__(16) unsigned short As[128][64];
    __shared__ __align__(16) unsigned short Bs[128][64];
    const int tid = threadIdx.x;
    const int lane = tid & 63;
    const int wid = tid >> 6;
    const int wr = wid >> 2, wc = wid & 3;
    const int bx = blockIdx.x & 7, by = blockIdx.x >> 3;
    const int brow = by * 128;
    const int bcol = bx * 128;

    f32x4 acc[4][2] = {};

    const int fr = tid >> 3;
    const int fk = (tid & 7) * 8;
    const int swz = (lane & 7) << 4;
    const int arow = wr * 64 + (lane & 15);
    const int brw  = wc * 32 + (lane & 15);
    const int klane = (lane >> 4) * 16;

    const int j0 = idx32[brow + fr];
    const int j1r = idx32[brow + 64 + fr];
    const int aoff0 = fr * 128 + ((fk * 2) ^ ((fr & 7) << 4));

    bool first = true;
#pragma unroll
    for (int term = 0; term < 3; ++term) {
        const int kaT = (term == 2) ? 256 : 0;
        const int kbT = (term == 1) ? 256 : 0;
        for (int kq = 0; kq < 4; ++kq) {
            if (!first) __syncthreads();
            first = false;
            const int ka0 = kaT + kq * 64;
            const int kb0 = kbT + kq * 64;
            {
                const char* src0 = (const char*)Gs + (size_t)j0 * 1024
                                 + ka0 * 2 + ((fk * 2) ^ ((j0 & 7) << 4));
                const char* src1 = (const char*)Gs + (size_t)j1r * 1024
                                 + ka0 * 2 + ((fk * 2) ^ ((j1r & 7) << 4));
                short8v v0 = *(const short8v*)src0;
                short8v v1 = *(const short8v*)src1;
                *(short8v*)((char*)&As[0][0] + aoff0) = v0;
                *(short8v*)((char*)&As[0][0] + 8192 + aoff0) = v1;
            }
#pragma unroll
            for (int l = 0; l < 2; ++l)
                gload16(dw2t + (size_t)(bcol + l * 64 + fr) * 512 + kb0 + fk,
                        (char*)&Bs[0][0] + l * 8192 + tid * 16);
            __syncthreads();
#pragma unroll
            for (int kk = 0; kk < 2; ++kk) {
                const int kb = (kk * 64 + klane) ^ swz;
                short8v af[4], bfv[2];
#pragma unroll
                for (int mi = 0; mi < 4; mi++)
                    af[mi] = *(const short8v*)((const char*)&As[arow + mi * 16][0] + kb);
#pragma unroll
                for (int ni = 0; ni < 2; ni++)
                    bfv[ni] = *(const short8v*)((const char*)&Bs[brw + ni * 16][0] + kb);
#pragma unroll
                for (int mi = 0; mi < 4; mi++)
#pragma unroll
                    for (int ni = 0; ni < 2; ni++)
                        acc[mi][ni] = __builtin_amdgcn_mfma_f32_16x16x32_bf16(
                            af[mi], bfv[ni], acc[mi][ni], 0, 0, 0);
            }
        }
    }

#pragma unroll
    for (int mi = 0; mi < 4; mi++) {
#pragma unroll
        for (int q = 0; q < 4; q++) {
            int row = brow + wr * 64 + mi * 16 + (lane >> 4) * 4 + q;
#pragma unroll
            for (int ni = 0; ni < 2; ni++) {
                int col = bcol + wc * 32 + ni * 16 + (lane & 15);
                outRec[(size_t)row * 1024 + col] = acc[mi][ni][q] + bias[col];
            }
        }
    }
}

extern "C" void kernel_launch(void* const* d_in, const int* in_sizes, int n_in,
                              void* d_out, int out_size, void* d_ws, size_t ws_size,
                              hipStream_t stream) {
    const float* x   = (const float*)d_in[0];
    const float* ew1 = (const float*)d_in[1];
    const float* eb1 = (const float*)d_in[2];
    const float* ew2 = (const float*)d_in[3];
    const float* eb2 = (const float*)d_in[4];
    const float* cw  = (const float*)d_in[5];
    const float* dw1 = (const float*)d_in[6];
    const float* db1 = (const float*)d_in[7];
    const float* dw2 = (const float*)d_in[8];
    const float* db2 = (const float*)d_in[9];
    float* out = (float*)d_out;
    float* ws  = (float*)d_ws;

    float* outIdx  = out;
    float* outDist = out + NROWS;
    float* outRec  = out + 2 * NROWS;
    float* outQ    = out + 2 * NROWS + (size_t)NROWS * IN_DIM;

    // layout (~21.7M floats). liveness: Hs (enc1->mm_pair) aliased by part
    // (vq+); Gs live dec1->dec2_gather; serial-launch ordered.
    float*          enc     = ws;                               // [0, 4.19M)
    unsigned short* Ae      = (unsigned short*)(ws + 4194304);  // [., 6.29M)
    unsigned short* Gs      = (unsigned short*)(ws + 6291456);  // [., 8.39M)
    unsigned short* Hs      = (unsigned short*)(ws + 8388608);  // [., 12.58M)
    ulonglong2*     part    = (ulonglong2*)(ws + 8388608);      // [., 10.49M)
    unsigned short* Be      = (unsigned short*)(ws + 18874368); // [., 20.97M)
    unsigned short* w1ts    = (unsigned short*)(ws + 20971520); // 1 MB
    unsigned short* ew2t    = (unsigned short*)(ws + 21233664);
    unsigned short* dw1t    = (unsigned short*)(ws + 21299200);
    unsigned short* dw2t    = (unsigned short*)(ws + 21364736);
    float*          c2      = ws + 21626880;
    int*            idx32   = (int*)(ws + 21635072);

    MMP p_enc2 = { Hs, ew2t, eb2, enc, Ae, 256, 512, 512, 256, 4, 1, 2 };
    MMP p_dec1 = { Be, dw1t, db1, nullptr, Gs, 256, 512, 512, 512, 4, 2, 2 };

    prep_all<<<2688, 256, 0, stream>>>(ew1, ew2, dw1, dw2, cw,
                                       w1ts, ew2t, dw1t, dw2t, Be, c2);
    enc1_fused<<<256, 512, 0, stream>>>(x, w1ts, eb1, Hs);
    mm_pair<<<384, 512, 0, stream>>>(p_enc2, p_dec1, 256);
    vq_mfma<<<dim3(NCB, 128), 512, 0, stream>>>(Ae, Be, c2, part);
    vq_combine<<<NROWS / 8, 512, 0, stream>>>(part, enc, cw, c2,
                                              outIdx, outDist, idx32, outQ);
    dec2_gather<<<1024, 512, 0, stream>>>(Gs, dw2t, db2, idx32, outRec);
}

// Round 16
// 189.178 us; speedup vs baseline: 1.2502x; 1.0086x over previous
//
#include <hip/hip_runtime.h>
#include <hip/hip_bf16.h>

#define NROWS   16384
#define IN_DIM  1024
#define ENC_DIM 256
#define KCW     8192
#define NCB     32          // codeword col-blocks of 256

typedef __attribute__((ext_vector_type(8))) short short8v;
typedef __attribute__((ext_vector_type(4))) float f32x4;
typedef unsigned long long u64;
typedef unsigned int u32;

// ---------------------------------------------------------------------------
// helpers
// ---------------------------------------------------------------------------
__device__ __forceinline__ unsigned short f2bf_rne(float x) {
    unsigned u = __float_as_uint(x);
    unsigned r = (u + 0x7fffu + ((u >> 16) & 1u)) >> 16;
    return (unsigned short)r;
}
__device__ __forceinline__ float bf2f(unsigned short h) {
    return __uint_as_float(((unsigned)h) << 16);
}
__device__ __forceinline__ int lex_lt(float d, int i, float D, int I) {
    return (d < D) || (d == D && i < I);
}
__device__ __forceinline__ void t2mrg(u64& b1, u64& b2, u64 c1, u64 c2) {
    u64 hi = (b1 > c1) ? b1 : c1;
    u64 lo2 = (b2 < c2) ? b2 : c2;
    b1 = (b1 < c1) ? b1 : c1;
    b2 = (hi < lo2) ? hi : lo2;
}
__device__ __forceinline__ void gload16(const void* g, void* l) {
    __builtin_amdgcn_global_load_lds(
        (__attribute__((address_space(1))) void*)g,
        (__attribute__((address_space(3))) void*)l, 16, 0, 0);
}

// ---------------------------------------------------------------------------
// prep: LDS-tiled transpose-split (coalesced loads, no strided overfetch).
// Tile 64k x 64n; same f2bf_rne math and byte layout as the scalar path ->
// bit-identical outputs.
// ---------------------------------------------------------------------------
__device__ __forceinline__ void ttile(const float* __restrict__ W,
                                      unsigned short* __restrict__ Wt,
                                      int K, int Ncols, int bk, int bn,
                                      int tid, float* tile /*[64*68]*/) {
    const int k0 = bk * 64, n0 = bn * 64;
#pragma unroll
    for (int p = 0; p < 4; ++p) {
        int kk = p * 16 + (tid >> 4);
        int nn = (tid & 15) * 4;
        float4 v = *(const float4*)(W + (size_t)(k0 + kk) * Ncols + n0 + nn);
        tile[kk * 68 + nn + 0] = v.x;
        tile[kk * 68 + nn + 1] = v.y;
        tile[kk * 68 + nn + 2] = v.z;
        tile[kk * 68 + nn + 3] = v.w;
    }
    __syncthreads();
    const int r = tid >> 2;               // n-row within tile (0..63)
    const int sgk = (tid & 3) * 16;       // k-segment (16 k per thread)
    const int n = n0 + r;
    const int m = (n & 7) << 4;
    char* rp = (char*)(Wt + (size_t)n * (2 * K));
    short8v h0, h1, l0, l1;
#pragma unroll
    for (int i = 0; i < 8; ++i) {
        float v = tile[(sgk + i) * 68 + r];
        unsigned short h = f2bf_rne(v);
        h0[i] = (short)h; l0[i] = (short)f2bf_rne(v - bf2f(h));
        float v2 = tile[(sgk + 8 + i) * 68 + r];
        unsigned short hh = f2bf_rne(v2);
        h1[i] = (short)hh; l1[i] = (short)f2bf_rne(v2 - bf2f(hh));
    }
    int b0 = (k0 + sgk) * 2,     b1 = (k0 + sgk + 8) * 2;
    int c0 = (K + k0 + sgk) * 2, c1 = (K + k0 + sgk + 8) * 2;
    *(short8v*)(rp + ((b0 & ~127) | ((b0 & 127) ^ m))) = h0;
    *(short8v*)(rp + ((b1 & ~127) | ((b1 & 127) ^ m))) = h1;
    *(short8v*)(rp + ((c0 & ~127) | ((c0 & 127) ^ m))) = l0;
    *(short8v*)(rp + ((c1 & ~127) | ((c1 & 127) ^ m))) = l1;
}

__global__ __launch_bounds__(256)
void prep_all(const float* __restrict__ ew1, const float* __restrict__ ew2,
              const float* __restrict__ dw1, const float* __restrict__ dw2,
              const float* __restrict__ cw,
              unsigned short* __restrict__ w1ts, unsigned short* __restrict__ ew2t,
              unsigned short* __restrict__ dw1t, unsigned short* __restrict__ dw2t,
              unsigned short* __restrict__ Be,   float* __restrict__ c2) {
    __shared__ float tile[64 * 68];
    const int b = blockIdx.x;
    const int tid = threadIdx.x;
    if (b < 64) {                      // ew1 [1024][256] -> w1ts, 16x4 tiles
        ttile(ew1, w1ts, 1024, 256, b & 15, b >> 4, tid, tile);
    } else if (b < 128) {              // dw2 [256][1024] -> dw2t, 4x16 tiles
        int l = b - 64;
        ttile(dw2, dw2t, 256, 1024, l & 3, l >> 2, tid, tile);
    } else if (b < 144) {              // ew2 [256][256] -> ew2t, 4x4 tiles
        int l = b - 128;
        ttile(ew2, ew2t, 256, 256, l & 3, l >> 2, tid, tile);
    } else if (b < 160) {              // dw1 [256][256] -> dw1t, 4x4 tiles
        int l = b - 144;
        ttile(dw1, dw1t, 256, 256, l & 3, l >> 2, tid, tile);
    } else {                           // cw split + fused rownorm c2
        int e = (b - 160) * 256 + tid;
        int row = e >> 6, kq = (e & 63) * 4;
        float4 v = ((const float4*)cw)[e];
        ushort4 hi, lo;
        hi.x = f2bf_rne(v.x); lo.x = f2bf_rne(v.x - bf2f(hi.x));
        hi.y = f2bf_rne(v.y); lo.y = f2bf_rne(v.y - bf2f(hi.y));
        hi.z = f2bf_rne(v.z); lo.z = f2bf_rne(v.z - bf2f(hi.z));
        hi.w = f2bf_rne(v.w); lo.w = f2bf_rne(v.w - bf2f(hi.w));
        const int m = (row & 7) << 4;
        char* rowp = (char*)(Be + (size_t)row * 512);
        int bh = kq * 2, bl = (256 + kq) * 2;
        *(ushort4*)(rowp + ((bh & ~127) | ((bh & 127) ^ m))) = hi;
        *(ushort4*)(rowp + ((bl & ~127) | ((bl & 127) ^ m))) = lo;
        float s = (v.x * v.x + v.y * v.y) + (v.z * v.z + v.w * v.w);
#pragma unroll
        for (int off = 1; off < 64; off <<= 1) s += __shfl_xor(s, off);
        if ((threadIdx.x & 63) == 0) c2[row] = s;
    }
}

// ---------------------------------------------------------------------------
// 512-thread (8-wave) split-bf16 MFMA GEMM body, LDS pool passed in.
// EPI: 1 = relu, C fp32 + Cs hi;  2 = relu, Cs hi+lo;  3 = no relu, C only.
// ---------------------------------------------------------------------------
struct MMP {
    const unsigned short* A;
    const unsigned short* Bt;
    const float* bias;
    float* C;
    unsigned short* Cs;
    int N, ars, brs, crs, KQ, EPI, gx;
};

__device__ void mm_device512(const MMP p, int bx, int by, int tid, char* lds) {
    unsigned short (*As)[64] = (unsigned short(*)[64])lds;
    unsigned short (*Bs)[64] = (unsigned short(*)[64])(lds + 16384);
    const int lane = tid & 63;
    const int wid = tid >> 6;
    const int wr = wid >> 2, wc = wid & 3;
    const int brow = by * 128;
    const int bcol = bx * 128;
    const int K = p.KQ * 64;

    f32x4 acc[4][2] = {};

    const int fr = tid >> 3;
    const int fk = (tid & 7) * 8;
    const int swz = (lane & 7) << 4;
    const int arow = wr * 64 + (lane & 15);
    const int brw  = wc * 32 + (lane & 15);
    const int klane = (lane >> 4) * 16;

    bool first = true;
#pragma unroll
    for (int term = 0; term < 3; ++term) {
        const int kaT = (term == 2) ? K : 0;
        const int kbT = (term == 1) ? K : 0;
        for (int kq = 0; kq < p.KQ; ++kq) {
            if (!first) __syncthreads();
            first = false;
            const int ka0 = kaT + kq * 64;
            const int kb0 = kbT + kq * 64;
#pragma unroll
            for (int l = 0; l < 2; ++l) {
                gload16(p.A  + (size_t)(brow + l * 64 + fr) * p.ars + ka0 + fk,
                        (char*)&As[0][0] + l * 8192 + tid * 16);
                gload16(p.Bt + (size_t)(bcol + l * 64 + fr) * p.brs + kb0 + fk,
                        (char*)&Bs[0][0] + l * 8192 + tid * 16);
            }
            __syncthreads();
#pragma unroll
            for (int kk = 0; kk < 2; ++kk) {
                const int kb = (kk * 64 + klane) ^ swz;
                short8v af[4], bfv[2];
#pragma unroll
                for (int mi = 0; mi < 4; mi++)
                    af[mi] = *(const short8v*)((const char*)&As[arow + mi * 16][0] + kb);
#pragma unroll
                for (int ni = 0; ni < 2; ni++)
                    bfv[ni] = *(const short8v*)((const char*)&Bs[brw + ni * 16][0] + kb);
#pragma unroll
                for (int mi = 0; mi < 4; mi++)
#pragma unroll
                    for (int ni = 0; ni < 2; ni++)
                        acc[mi][ni] = __builtin_amdgcn_mfma_f32_16x16x32_bf16(
                            af[mi], bfv[ni], acc[mi][ni], 0, 0, 0);
            }
        }
    }

#pragma unroll
    for (int mi = 0; mi < 4; mi++) {
#pragma unroll
        for (int q = 0; q < 4; q++) {
            int row = brow + wr * 64 + mi * 16 + (lane >> 4) * 4 + q;
            const int m = (row & 7) << 4;
            char* rp = (char*)(p.Cs + (size_t)row * p.crs);
#pragma unroll
            for (int ni = 0; ni < 2; ni++) {
                int col = bcol + wc * 32 + ni * 16 + (lane & 15);
                float v = acc[mi][ni][q] + p.bias[col];
                if (p.EPI != 3) v = fmaxf(v, 0.f);
                if (p.EPI & 1) p.C[(size_t)row * p.N + col] = v;
                if (p.EPI != 3) {
                    unsigned short hi = f2bf_rne(v);
                    int bh = col * 2;
                    *(unsigned short*)(rp + ((bh & ~127) | ((bh & 127) ^ m))) = hi;
                    if (p.EPI == 2) {
                        unsigned short lo = f2bf_rne(v - bf2f(hi));
                        int bl = (256 + col) * 2;
                        *(unsigned short*)(rp + ((bl & ~127) | ((bl & 127) ^ m))) = lo;
                    }
                }
            }
        }
    }
}

__global__ __launch_bounds__(512)
void mm_pair(MMP p0, MMP p1, int n0) {
    __shared__ __align__(16) char pool[32768];
    if ((int)blockIdx.x < n0) {
        mm_device512(p0, blockIdx.x % p0.gx, blockIdx.x / p0.gx, threadIdx.x, pool);
    } else {
        int b = blockIdx.x - n0;
        mm_device512(p1, b % p1.gx, b / p1.gx, threadIdx.x, pool);
    }
}

// ---------------------------------------------------------------------------
// enc1 (unchanged): single pass over x, 3 terms interleaved per k-step.
// ---------------------------------------------------------------------------
__global__ __launch_bounds__(512)
void enc1_fused(const float* __restrict__ x,
                const unsigned short* __restrict__ w1ts,
                const float* __restrict__ bias,
                unsigned short* __restrict__ Hs) {
    __shared__ __align__(16) unsigned short Ah[64][64];
    __shared__ __align__(16) unsigned short Al[64][64];
    __shared__ __align__(16) unsigned short Bh[256][64];
    __shared__ __align__(16) unsigned short Bl[256][64];
    const int tid = threadIdx.x;
    const int lane = tid & 63;
    const int wid = tid >> 6;
    const int wr = wid >> 2, wc = wid & 3;
    const int brow = blockIdx.x * 64;

    f32x4 acc[2][4] = {};

    const int fr = tid >> 3;
    const int fk = (tid & 7) * 8;
    const int swz = (lane & 7) << 4;
    const int arow = wr * 32 + (lane & 15);
    const int brw  = wc * 64 + (lane & 15);
    const int klane = (lane >> 4) * 16;
    const int aoff = fr * 128 + ((fk * 2) ^ ((fr & 7) << 4));

    float4 c0, c1, n0, n1;
    {
        const float* xp = x + (size_t)(brow + fr) * 1024 + fk;
        c0 = *(const float4*)xp; c1 = *(const float4*)(xp + 4);
    }

    for (int s = 0; s < 16; ++s) {
        const int k0 = s * 64;
        if (s) __syncthreads();
        {
            float vv[8] = { c0.x, c0.y, c0.z, c0.w, c1.x, c1.y, c1.z, c1.w };
            short8v uh, ul;
#pragma unroll
            for (int i = 0; i < 8; i++) {
                unsigned short h = f2bf_rne(vv[i]);
                uh[i] = (short)h;
                ul[i] = (short)f2bf_rne(vv[i] - bf2f(h));
            }
            *(short8v*)((char*)&Ah[0][0] + aoff) = uh;
            *(short8v*)((char*)&Al[0][0] + aoff) = ul;
        }
#pragma unroll
        for (int l = 0; l < 4; ++l) {
            gload16(w1ts + (size_t)(l * 64 + fr) * 2048 + k0 + fk,
                    (char*)&Bh[0][0] + l * 8192 + tid * 16);
            gload16(w1ts + (size_t)(l * 64 + fr) * 2048 + 1024 + k0 + fk,
                    (char*)&Bl[0][0] + l * 8192 + tid * 16);
        }
        if (s + 1 < 16) {
            const float* xp = x + (size_t)(brow + fr) * 1024 + k0 + 64 + fk;
            n0 = *(const float4*)xp; n1 = *(const float4*)(xp + 4);
        }
        __syncthreads();
#pragma unroll
        for (int kk = 0; kk < 2; ++kk) {
            const int kb = (kk * 64 + klane) ^ swz;
            short8v ah[2], al[2], bh[4], bl[4];
#pragma unroll
            for (int mi = 0; mi < 2; mi++) {
                ah[mi] = *(const short8v*)((const char*)&Ah[arow + mi * 16][0] + kb);
                al[mi] = *(const short8v*)((const char*)&Al[arow + mi * 16][0] + kb);
            }
#pragma unroll
            for (int ni = 0; ni < 4; ni++) {
                bh[ni] = *(const short8v*)((const char*)&Bh[brw + ni * 16][0] + kb);
                bl[ni] = *(const short8v*)((const char*)&Bl[brw + ni * 16][0] + kb);
            }
#pragma unroll
            for (int mi = 0; mi < 2; mi++)
#pragma unroll
                for (int ni = 0; ni < 4; ni++) {
                    acc[mi][ni] = __builtin_amdgcn_mfma_f32_16x16x32_bf16(
                        ah[mi], bh[ni], acc[mi][ni], 0, 0, 0);
                    acc[mi][ni] = __builtin_amdgcn_mfma_f32_16x16x32_bf16(
                        ah[mi], bl[ni], acc[mi][ni], 0, 0, 0);
                    acc[mi][ni] = __builtin_amdgcn_mfma_f32_16x16x32_bf16(
                        al[mi], bh[ni], acc[mi][ni], 0, 0, 0);
                }
        }
        c0 = n0; c1 = n1;
    }

#pragma unroll
    for (int mi = 0; mi < 2; mi++) {
#pragma unroll
        for (int q = 0; q < 4; q++) {
            int row = brow + wr * 32 + mi * 16 + (lane >> 4) * 4 + q;
            const int m = (row & 7) << 4;
            char* rp = (char*)(Hs + (size_t)row * 512);
#pragma unroll
            for (int ni = 0; ni < 4; ni++) {
                int col = wc * 64 + ni * 16 + (lane & 15);
                float v = fmaxf(acc[mi][ni][q] + bias[col], 0.f);
                unsigned short hi = f2bf_rne(v);
                unsigned short lo = f2bf_rne(v - bf2f(hi));
                int bh_ = col * 2, bl_ = (256 + col) * 2;
                *(unsigned short*)(rp + ((bh_ & ~127) | ((bh_ & 127) ^ m))) = hi;
                *(unsigned short*)(rp + ((bl_ & ~127) | ((bl_ & 127) ^ m))) = lo;
            }
        }
    }
}

// ---------------------------------------------------------------------------
// VQ MFMA kernel — standalone (VGPR 64, 3 blocks/CU): hi-only bf16 d2-key
// GEMM (K=256), 128x256 tile, 512 threads, swapped-operand MFMA,
// u32-packed top-2.
// ---------------------------------------------------------------------------
__global__ __launch_bounds__(512)
void vq_mfma(const unsigned short* __restrict__ Ae,
             const unsigned short* __restrict__ Be,
             const float* __restrict__ c2,
             ulonglong2* __restrict__ part) {
    __shared__ __align__(16) unsigned short As[128][64];
    __shared__ __align__(16) unsigned short Bs[256][64];
    __shared__ u32 s1[128][4];
    __shared__ u32 s2[128][4];

    const int tid  = threadIdx.x;
    const int lane = tid & 63;
    const int wid  = tid >> 6;
    const int wr   = wid >> 2;
    const int wc   = wid & 3;
    const int brow = blockIdx.y * 128;
    const int bcol = blockIdx.x * 256;

    f32x4 acc[4][4] = {};

    const int fr = tid >> 3;
    const int fk = (tid & 7) * 8;
    const int swz   = (lane & 7) << 4;
    const int arow  = wr * 64 + (lane & 15);
    const int brw   = wc * 64 + (lane & 15);
    const int klane = (lane >> 4) * 16;

    for (int s = 0; s < 4; ++s) {
        const int k0 = s * 64;
        if (s) __syncthreads();
#pragma unroll
        for (int l = 0; l < 2; ++l)
            gload16(Ae + (size_t)(brow + l * 64 + fr) * 256 + k0 + fk,
                    (char*)&As[0][0] + l * 8192 + tid * 16);
#pragma unroll
        for (int l = 0; l < 4; ++l)
            gload16(Be + (size_t)(bcol + l * 64 + fr) * 512 + k0 + fk,
                    (char*)&Bs[0][0] + l * 8192 + tid * 16);
        __syncthreads();
#pragma unroll
        for (int kk = 0; kk < 2; ++kk) {
            const int kb = (kk * 64 + klane) ^ swz;
            short8v af[4], bfv[4];
#pragma unroll
            for (int mi = 0; mi < 4; mi++)
                af[mi] = *(const short8v*)((const char*)&As[arow + mi * 16][0] + kb);
#pragma unroll
            for (int ni = 0; ni < 4; ni++)
                bfv[ni] = *(const short8v*)((const char*)&Bs[brw + ni * 16][0] + kb);
#pragma unroll
            for (int mi = 0; mi < 4; mi++)
#pragma unroll
                for (int ni = 0; ni < 4; ni++)
                    acc[mi][ni] = __builtin_amdgcn_mfma_f32_16x16x32_bf16(
                        bfv[ni], af[mi], acc[mi][ni], 0, 0, 0);
        }
    }

    const int qrow = lane & 15;
    const int cq   = (lane >> 4) * 4;
    float4 c2q[4];
#pragma unroll
    for (int ni = 0; ni < 4; ni++)
        c2q[ni] = *(const float4*)&c2[bcol + wc * 64 + ni * 16 + cq];

#pragma unroll
    for (int mi = 0; mi < 4; mi++) {
        u32 b1 = 0xFFFFFFFFu, b2 = 0xFFFFFFFFu;
#pragma unroll
        for (int ni = 0; ni < 4; ni++) {
            const float* cp = (const float*)&c2q[ni];
#pragma unroll
            for (int r = 0; r < 4; r++) {
                float dk = fmaf(-2.0f, acc[mi][ni][r], cp[r]);
                dk = fmaxf(dk, 0.0f);
                u32 k = (__float_as_uint(dk) & ~255u)
                      | (u32)(wc * 64 + ni * 16 + cq + r);
                u32 mx = max(k, b1);
                b1 = min(k, b1);
                b2 = min(mx, b2);
            }
        }
#pragma unroll
        for (int off = 16; off < 64; off <<= 1) {
            u32 o1 = __shfl_xor(b1, off);
            u32 o2 = __shfl_xor(b2, off);
            u32 mx = max(b1, o1);
            b1 = min(b1, o1);
            b2 = min(min(b2, o2), mx);
        }
        if (lane < 16) {
            int rl = wr * 64 + mi * 16 + qrow;
            s1[rl][wc] = b1;
            s2[rl][wc] = b2;
        }
    }
    __syncthreads();
    if (tid < 128) {
        u32 b1 = s1[tid][0], b2 = s2[tid][0];
#pragma unroll
        for (int w = 1; w < 4; w++) {
            u32 c1 = s1[tid][w], cc2 = s2[tid][w];
            u32 mx = max(b1, c1);
            b1 = min(b1, c1);
            b2 = min(min(b2, cc2), mx);
        }
        ulonglong2 pk;
        pk.x = ((u64)b1 << 32) | (u32)(bcol + (b1 & 255u));
        pk.y = ((u64)b2 << 32) | (u32)(bcol + (b2 & 255u));
        part[(size_t)(brow + tid) * NCB + blockIdx.x] = pk;
    }
}

// ---------------------------------------------------------------------------
// combine: 8 rows/block, global approx top-2 -> exact fp32 rescore, fused
// outQ gather (lanes already hold w1/w2).
// ---------------------------------------------------------------------------
__global__ __launch_bounds__(512)
void vq_combine(const ulonglong2* __restrict__ part,
                const float* __restrict__ enc,
                const float* __restrict__ cw,
                const float* __restrict__ c2,
                float* __restrict__ outIdx,
                float* __restrict__ outDist,
                int* __restrict__ idx32,
                float* __restrict__ outQ) {
    const int row  = blockIdx.x * 8 + (threadIdx.x >> 6);
    const int lane = threadIdx.x & 63;

    u64 b1 = ~0ull, b2 = ~0ull;
    if (lane < NCB) {
        ulonglong2 pk = part[(size_t)row * NCB + lane];
        b1 = pk.x; b2 = pk.y;
    }
#pragma unroll
    for (int off = 1; off < 64; off <<= 1) {
        u64 c1 = __shfl_xor(b1, off);
        u64 cc2 = __shfl_xor(b2, off);
        t2mrg(b1, b2, c1, cc2);
    }
    int j1 = (int)(b1 & 0xffffffffu);
    int j2 = (int)(b2 & 0xffffffffu);

    float4 e4 = ((const float4*)(enc + (size_t)row * 256))[lane];
    float4 w1 = ((const float4*)(cw + (size_t)j1 * 256))[lane];
    float4 w2 = ((const float4*)(cw + (size_t)j2 * 256))[lane];
    float s1 = fmaf(e4.x, w1.x, fmaf(e4.y, w1.y, fmaf(e4.z, w1.z, e4.w * w1.w)));
    float s2 = fmaf(e4.x, w2.x, fmaf(e4.y, w2.y, fmaf(e4.z, w2.z, e4.w * w2.w)));
    float sx = (e4.x * e4.x + e4.y * e4.y) + (e4.z * e4.z + e4.w * e4.w);
#pragma unroll
    for (int off = 1; off < 64; off <<= 1) {
        s1 += __shfl_xor(s1, off);
        s2 += __shfl_xor(s2, off);
        sx += __shfl_xor(sx, off);
    }
    float d1 = sqrtf(fmaxf(sx + c2[j1] - 2.0f * s1, 0.f));
    float d2 = sqrtf(fmaxf(sx + c2[j2] - 2.0f * s2, 0.f));
    float bd; int bi;
    if (lex_lt(d1, j1, d2, j2)) { bd = d1; bi = j1; }
    else                        { bd = d2; bi = j2; }
    float4 wq = (bi == j1) ? w1 : w2;
    ((float4*)(outQ + (size_t)row * ENC_DIM))[lane] = wq;
    if (lane == 0) {
        outIdx[row]  = (float)bi;
        outDist[row] = bd;
        idx32[row]   = bi;
    }
}

// ---------------------------------------------------------------------------
// dec2_gather: outRec[row] = Gs[idx32[row]] @ dw2t + db2  (no relu, fp32 out)
// A reg-staged from Gs[j] with source-side (j&7) un-swizzle + dest (fr&7)
// re-swizzle; B via gload16 from dw2t. Bit-identical to compute-then-gather.
// ---------------------------------------------------------------------------
__global__ __launch_bounds__(512)
void dec2_gather(const unsigned short* __restrict__ Gs,
                 const unsigned short* __restrict__ dw2t,
                 const float* __restrict__ bias,
                 const int* __restrict__ idx32,
                 float* __restrict__ outRec) {
    __shared__ __align__(16) unsigned short As[128][64];
    __shared__ __align__(16) unsigned short Bs[128][64];
    const int tid = threadIdx.x;
    const int lane = tid & 63;
    const int wid = tid >> 6;
    const int wr = wid >> 2, wc = wid & 3;
    const int bx = blockIdx.x & 7, by = blockIdx.x >> 3;
    const int brow = by * 128;
    const int bcol = bx * 128;

    f32x4 acc[4][2] = {};

    const int fr = tid >> 3;
    const int fk = (tid & 7) * 8;
    const int swz = (lane & 7) << 4;
    const int arow = wr * 64 + (lane & 15);
    const int brw  = wc * 32 + (lane & 15);
    const int klane = (lane >> 4) * 16;

    const int j0 = idx32[brow + fr];
    const int j1r = idx32[brow + 64 + fr];
    const int aoff0 = fr * 128 + ((fk * 2) ^ ((fr & 7) << 4));

    bool first = true;
#pragma unroll
    for (int term = 0; term < 3; ++term) {
        const int kaT = (term == 2) ? 256 : 0;
        const int kbT = (term == 1) ? 256 : 0;
        for (int kq = 0; kq < 4; ++kq) {
            if (!first) __syncthreads();
            first = false;
            const int ka0 = kaT + kq * 64;
            const int kb0 = kbT + kq * 64;
            {
                const char* src0 = (const char*)Gs + (size_t)j0 * 1024
                                 + ka0 * 2 + ((fk * 2) ^ ((j0 & 7) << 4));
                const char* src1 = (const char*)Gs + (size_t)j1r * 1024
                                 + ka0 * 2 + ((fk * 2) ^ ((j1r & 7) << 4));
                short8v v0 = *(const short8v*)src0;
                short8v v1 = *(const short8v*)src1;
                *(short8v*)((char*)&As[0][0] + aoff0) = v0;
                *(short8v*)((char*)&As[0][0] + 8192 + aoff0) = v1;
            }
#pragma unroll
            for (int l = 0; l < 2; ++l)
                gload16(dw2t + (size_t)(bcol + l * 64 + fr) * 512 + kb0 + fk,
                        (char*)&Bs[0][0] + l * 8192 + tid * 16);
            __syncthreads();
#pragma unroll
            for (int kk = 0; kk < 2; ++kk) {
                const int kb = (kk * 64 + klane) ^ swz;
                short8v af[4], bfv[2];
#pragma unroll
                for (int mi = 0; mi < 4; mi++)
                    af[mi] = *(const short8v*)((const char*)&As[arow + mi * 16][0] + kb);
#pragma unroll
                for (int ni = 0; ni < 2; ni++)
                    bfv[ni] = *(const short8v*)((const char*)&Bs[brw + ni * 16][0] + kb);
#pragma unroll
                for (int mi = 0; mi < 4; mi++)
#pragma unroll
                    for (int ni = 0; ni < 2; ni++)
                        acc[mi][ni] = __builtin_amdgcn_mfma_f32_16x16x32_bf16(
                            af[mi], bfv[ni], acc[mi][ni], 0, 0, 0);
            }
        }
    }

#pragma unroll
    for (int mi = 0; mi < 4; mi++) {
#pragma unroll
        for (int q = 0; q < 4; q++) {
            int row = brow + wr * 64 + mi * 16 + (lane >> 4) * 4 + q;
#pragma unroll
            for (int ni = 0; ni < 2; ni++) {
                int col = bcol + wc * 32 + ni * 16 + (lane & 15);
                outRec[(size_t)row * 1024 + col] = acc[mi][ni][q] + bias[col];
            }
        }
    }
}

extern "C" void kernel_launch(void* const* d_in, const int* in_sizes, int n_in,
                              void* d_out, int out_size, void* d_ws, size_t ws_size,
                              hipStream_t stream) {
    const float* x   = (const float*)d_in[0];
    const float* ew1 = (const float*)d_in[1];
    const float* eb1 = (const float*)d_in[2];
    const float* ew2 = (const float*)d_in[3];
    const float* eb2 = (const float*)d_in[4];
    const float* cw  = (const float*)d_in[5];
    const float* dw1 = (const float*)d_in[6];
    const float* db1 = (const float*)d_in[7];
    const float* dw2 = (const float*)d_in[8];
    const float* db2 = (const float*)d_in[9];
    float* out = (float*)d_out;
    float* ws  = (float*)d_ws;

    float* outIdx  = out;
    float* outDist = out + NROWS;
    float* outRec  = out + 2 * NROWS;
    float* outQ    = out + 2 * NROWS + (size_t)NROWS * IN_DIM;

    // layout (~21.7M floats). liveness: Hs (enc1->mm_pair) aliased by part
    // (vq+); Gs live dec1->dec2_gather; serial-launch ordered.
    float*          enc     = ws;                               // [0, 4.19M)
    unsigned short* Ae      = (unsigned short*)(ws + 4194304);  // [., 6.29M)
    unsigned short* Gs      = (unsigned short*)(ws + 6291456);  // [., 8.39M)
    unsigned short* Hs      = (unsigned short*)(ws + 8388608);  // [., 12.58M)
    ulonglong2*     part    = (ulonglong2*)(ws + 8388608);      // [., 10.49M)
    unsigned short* Be      = (unsigned short*)(ws + 18874368); // [., 20.97M)
    unsigned short* w1ts    = (unsigned short*)(ws + 20971520); // 1 MB
    unsigned short* ew2t    = (unsigned short*)(ws + 21233664);
    unsigned short* dw1t    = (unsigned short*)(ws + 21299200);
    unsigned short* dw2t    = (unsigned short*)(ws + 21364736);
    float*          c2      = ws + 21626880;
    int*            idx32   = (int*)(ws + 21635072);

    MMP p_enc2 = { Hs, ew2t, eb2, enc, Ae, 256, 512, 512, 256, 4, 1, 2 };
    MMP p_dec1 = { Be, dw1t, db1, nullptr, Gs, 256, 512, 512, 512, 4, 2, 2 };

    prep_all<<<2208, 256, 0, stream>>>(ew1, ew2, dw1, dw2, cw,
                                       w1ts, ew2t, dw1t, dw2t, Be, c2);
    enc1_fused<<<256, 512, 0, stream>>>(x, w1ts, eb1, Hs);
    mm_pair<<<384, 512, 0, stream>>>(p_enc2, p_dec1, 256);
    vq_mfma<<<dim3(NCB, 128), 512, 0, stream>>>(Ae, Be, c2, part);
    vq_combine<<<NROWS / 8, 512, 0, stream>>>(part, enc, cw, c2,
                                              outIdx, outDist, idx32, outQ);
    dec2_gather<<<1024, 512, 0, stream>>>(Gs, dw2t, db2, idx32, outRec);
}